// Round 2
// baseline (662.629 us; speedup 1.0000x reference)
//
#include <hip/hip_runtime.h>
#include <math.h>

#define BB 8
#define NN 2048
#define HID 768
#define NHEADS 4
#define VOCAB 15
#define ALPHA 0.2f
#define NEGV -9e15f
#define MTOT (BB * NN)  // 16384

using short4v = __attribute__((ext_vector_type(4))) short;
using short8v = __attribute__((ext_vector_type(8))) short;
using f32x4 = __attribute__((ext_vector_type(4))) float;

__device__ __forceinline__ short f2bf(float f) {
  union { float f; unsigned u; } x;
  x.f = f;
  unsigned r = x.u + 0x7fffu + ((x.u >> 16) & 1u);
  return (short)(r >> 16);
}

__device__ __forceinline__ float b2f(short h) {
  union { unsigned u; float f; } y;
  y.u = ((unsigned)(unsigned short)h) << 16;
  return y.f;
}

__device__ __forceinline__ void cp16(const void* g, void* l) {
  __builtin_amdgcn_global_load_lds(
      (const __attribute__((address_space(1))) unsigned int*)g,
      (__attribute__((address_space(3))) unsigned int*)l, 16, 0, 0);
}

// pack 8 bytes' low nibbles (LE order) into 32 bits
__device__ __forceinline__ unsigned long long nibcompress(unsigned long long x) {
  x = (x | (x >> 4)) & 0x00FF00FF00FF00FFull;
  x = (x | (x >> 8)) & 0x0000FFFF0000FFFFull;
  x = (x | (x >> 16)) & 0x00000000FFFFFFFFull;
  return x;
}

#define MEMFENCE asm volatile("" ::: "memory")
#define SBAR()                         \
  do {                                 \
    MEMFENCE;                          \
    __builtin_amdgcn_s_barrier();      \
    MEMFENCE;                          \
  } while (0)

// ---------------------------------------------------------------------------
// Mega-setup (unchanged): adj bit-pack; zero accumulators; vocab bitmasks;
// W_out transpose; TW partials.
// ---------------------------------------------------------------------------
#define PACK_B 32768
#define ZERO_B 308
#define NFM_B 64
#define TRAN_B 2304  // 96 x 24 tiles of 32x32
#define TW_B 192     // 12 col-chunks x 16 k-chunks
__global__ __launch_bounds__(256) void setup_kernel(
    const int* __restrict__ adj, unsigned long long* __restrict__ packed,
    float* __restrict__ zbase, const int* __restrict__ nf,
    unsigned long long* __restrict__ nfm, const float* __restrict__ W_out,
    short* __restrict__ Wt_o, const float* __restrict__ table,
    const float* __restrict__ W_heads, float* __restrict__ TWp) {
  const int bid = blockIdx.x;
  const int tid = threadIdx.x;
  if (bid < PACK_B) {
    __shared__ unsigned long long nibq[32];
    long base = (long)bid * 1024;
    int4 a = *(const int4*)(adj + base + tid * 4);
    unsigned nib = (a.x > 0 ? 1u : 0u) | (a.y > 0 ? 2u : 0u) |
                   (a.z > 0 ? 4u : 0u) | (a.w > 0 ? 8u : 0u);
    ((unsigned char*)nibq)[tid] = (unsigned char)nib;
    __syncthreads();
    if (tid < 16) {
      unsigned long long lo = nibcompress(nibq[2 * tid]);
      unsigned long long hi = nibcompress(nibq[2 * tid + 1]);
      packed[(base >> 6) + tid] = lo | (hi << 32);
    }
  } else if (bid < PACK_B + ZERO_B) {
    zbase[(bid - PACK_B) * 256 + tid] = 0.f;
  } else if (bid < PACK_B + ZERO_B + NFM_B) {
    int r = bid - PACK_B - ZERO_B;  // 0..63
    int b = r >> 3, c = r & 7;
    int w = tid >> 6;
    int j = c * 256 + tid;
    int nfv = nf[b * NN + j];
#pragma unroll
    for (int v = 0; v < VOCAB; ++v) {
      unsigned long long m = __ballot(nfv == v);
      if ((tid & 63) == 0) nfm[((long)b * VOCAB + v) * 32 + c * 4 + w] = m;
    }
  } else if (bid < PACK_B + ZERO_B + NFM_B + TRAN_B) {
    // W_out transpose (3072x768 -> bf16 768x3072)
    __shared__ float t[32][33];
    int r2 = bid - PACK_B - ZERO_B - NFM_B;
    const int K = NHEADS * HID, N = HID;
    int k0 = (r2 % 96) * 32, n0 = (r2 / 96) * 32;
    int tx = tid & 31, ty = tid >> 5;
#pragma unroll
    for (int i = 0; i < 32; i += 8)
      t[ty + i][tx] = W_out[(long)(k0 + ty + i) * N + n0 + tx];
    __syncthreads();
#pragma unroll
    for (int i = 0; i < 32; i += 8)
      Wt_o[(long)(n0 + ty + i) * K + k0 + tx] = f2bf(t[tx][ty + i]);
  } else {
    // TW partial: col-chunk cx (256 cols), k-chunk ky (48 k) -> disjoint slot
    __shared__ float tbl[VOCAB][48];
    int r3 = bid - PACK_B - ZERO_B - NFM_B - TRAN_B;  // 0..191
    const int cx = r3 % 12, ky = r3 / 12;
    const int c = cx * 256 + tid;
    const int h = (cx * 256) / HID;
    const int n = c - h * HID;
    const int k0 = ky * 48;
    for (int idx = tid; idx < VOCAB * 48; idx += 256)
      tbl[idx / 48][idx % 48] = table[(idx / 48) * HID + k0 + idx % 48];
    __syncthreads();
    float acc[VOCAB];
#pragma unroll
    for (int v = 0; v < VOCAB; ++v) acc[v] = 0.f;
    const float* wp = W_heads + (long)h * HID * HID + (long)k0 * HID + n;
#pragma unroll 8
    for (int kk = 0; kk < 48; ++kk) {
      float w = wp[(long)kk * HID];
#pragma unroll
      for (int v = 0; v < VOCAB; ++v) acc[v] = fmaf(tbl[v][kk], w, acc[v]);
    }
#pragma unroll
    for (int v = 0; v < VOCAB; ++v)
      TWp[((long)ky * VOCAB + v) * (NHEADS * HID) + c] = acc[v];
  }
}

// ---------------------------------------------------------------------------
// Fused: reduce 16 TW partials; emit TWb (bf16 hi/lo, MFMA B-slot layout:
// [k][0..15]=hi, [16..31]=hi, [32..47]=lo, [48..63]=lo, slots 15/31/47/63=0)
// and a-dot partials into TW1/TW2. grid 12.
// ---------------------------------------------------------------------------
__global__ __launch_bounds__(256) void tw_finish_kernel(
    const float* __restrict__ TWp, short* __restrict__ TWb,
    const float* __restrict__ a_heads, float* __restrict__ TW1,
    float* __restrict__ TW2) {
  const int tid = threadIdx.x;
  const int c = blockIdx.x * 256 + tid;  // 0..3071 (global k)
  const int h = (blockIdx.x * 256) / HID;  // uniform per block
  const int n = c - h * HID;
  const float a1 = a_heads[h * 2 * HID + n];
  const float a2 = a_heads[h * 2 * HID + HID + n];
  const int lane = tid & 63;
  const int wv = tid >> 6;
  __shared__ float red[4][2 * VOCAB];

  short* tb = TWb + ((long)c << 6);
  float s1[VOCAB], s2[VOCAB];
#pragma unroll
  for (int v = 0; v < VOCAB; ++v) {
    float s = 0.f;
#pragma unroll
    for (int ky = 0; ky < 16; ++ky)
      s += TWp[((long)ky * VOCAB + v) * (NHEADS * HID) + c];
    short hi = f2bf(s);
    short lo = f2bf(s - b2f(hi));
    tb[v] = hi;
    tb[16 + v] = hi;
    tb[32 + v] = lo;
    tb[48 + v] = lo;
    s1[v] = s * a1;
    s2[v] = s * a2;
  }
  tb[15] = 0; tb[31] = 0; tb[47] = 0; tb[63] = 0;
#pragma unroll
  for (int off = 1; off < 64; off <<= 1)
#pragma unroll
    for (int v = 0; v < VOCAB; ++v) {
      s1[v] += __shfl_xor(s1[v], off);
      s2[v] += __shfl_xor(s2[v], off);
    }
  if (lane == 0) {
#pragma unroll
    for (int v = 0; v < VOCAB; ++v) {
      red[wv][v] = s1[v];
      red[wv][VOCAB + v] = s2[v];
    }
  }
  __syncthreads();
  if (tid < 2 * VOCAB) {
    float s = red[0][tid] + red[1][tid] + red[2][tid] + red[3][tid];
    float* dst = (tid < VOCAB) ? (TW1 + h * VOCAB + tid)
                               : (TW2 + h * VOCAB + tid - VOCAB);
    atomicAdd(dst, s);
  }
}

// ---------------------------------------------------------------------------
// P16 via popcount; writes P2 bf16 hi/lo in MFMA A-slot layout:
// [h][row][0..15]=hi (slot15=0), [16..31]=lo (slot31=0).
// ---------------------------------------------------------------------------
__global__ __launch_bounds__(256) void p16_kernel(
    const int* __restrict__ nf, const unsigned* __restrict__ padj32,
    const unsigned* __restrict__ nfm32, const float* __restrict__ TW1,
    const float* __restrict__ TW2, short* __restrict__ P2) {
  const int t = threadIdx.x;
  const int wv = t >> 6;
  const int lane = t & 63;
  const int rowm = blockIdx.x * 4 + wv;
  const int b = rowm >> 11;
  __shared__ float cnts[4][16];

  unsigned a = padj32[(long)rowm * 64 + lane];
  const unsigned* nb = nfm32 + (long)b * VOCAB * 64 + lane;
  int cnt[VOCAB];
#pragma unroll
  for (int v = 0; v < VOCAB; ++v) cnt[v] = __popc(a & nb[v * 64]);
#pragma unroll
  for (int off = 1; off < 64; off <<= 1)
#pragma unroll
    for (int v = 0; v < VOCAB; ++v) cnt[v] += __shfl_xor(cnt[v], off);
  int cntsum = 0;
#pragma unroll
  for (int v = 0; v < VOCAB; ++v) cntsum += cnt[v];
  const bool use_full = (cntsum == 0);  // wave-uniform
  if (use_full) {
#pragma unroll
    for (int v = 0; v < VOCAB; ++v) cnt[v] = __popc(nb[v * 64]);
#pragma unroll
    for (int off = 1; off < 64; off <<= 1)
#pragma unroll
      for (int v = 0; v < VOCAB; ++v) cnt[v] += __shfl_xor(cnt[v], off);
  }
  if (lane < 16) cnts[wv][lane] = (lane < VOCAB) ? (float)cnt[lane] : 0.f;
  __syncthreads();

  const int h = lane >> 4;
  const int v = lane & 15;
  const int nfi = nf[b * NN + (rowm & 2047)];
  float cvf = cnts[wv][v];
  bool valid = (v < VOCAB) && (cvf > 0.f);
  float logit = 0.f;
  if (!use_full) {
    float s = TW1[h * VOCAB + nfi] + ((v < VOCAB) ? TW2[h * VOCAB + v] : 0.f);
    logit = s > 0.f ? s : ALPHA * s;
  }
  float mv = valid ? logit : -INFINITY;
#pragma unroll
  for (int off = 1; off < 16; off <<= 1) mv = fmaxf(mv, __shfl_xor(mv, off));
  float pv = valid ? cvf * __expf(logit - mv) : 0.f;
  float sum = pv;
#pragma unroll
  for (int off = 1; off < 16; off <<= 1) sum += __shfl_xor(sum, off);
  float pn = pv / sum;  // 0 for invalid lanes (incl. v==15)
  short hi = f2bf(pn);
  short lo = f2bf(pn - b2f(hi));
  long pb = ((long)h * 16384 + rowm) << 5;
  P2[pb + v] = hi;
  P2[pb + 16 + v] = lo;
}

// ---------------------------------------------------------------------------
// bf16 MFMA GEMM, 256x256 tile, BK=64, 512 threads (8 waves, 2Mx4N),
// 4 phases/K-tile; B double-buffered via global_load_lds; A-tile GENERATED
// in-kernel at q3 (single-buffered: LDS-A is dead after q2's reads).
//  MODE 0: A = ELU(P16·TW) via expand-MFMA (P2 hi/lo A-slots x TWb hi/lo
//          B-vectors -> f32-accurate); epilogue: a-dot atomics + transposed
//          bf16 Ct.
//  MODE 3: A = exp(leaky(wh1+wh2) - m[row]) * maskbit via VALU; epilogue:
//          scale by inv_s[row], ELU, mean-pool atomics.
// ---------------------------------------------------------------------------
template <int MODE>
__global__ __launch_bounds__(512, 2) void mfma_gemm(
    const short* __restrict__ Bm, int K, int ldb, long sB,
    const short* __restrict__ P2, const short* __restrict__ TWb,
    const float* __restrict__ Wh1r, const float* __restrict__ Wh2r,
    const unsigned long long* __restrict__ packed,
    const float* __restrict__ mrow, const float* __restrict__ invs,
    float* __restrict__ Cf, short* __restrict__ Ct,
    const float* __restrict__ a_vec, float* __restrict__ Wh1g,
    float* __restrict__ Wh2g) {
  __shared__ short Bs[2][16384];  // 64 KiB B double-buffer
  __shared__ short At[16384];     // 32 KiB generated A tile (256 x 64)
  __shared__ float whl[2048];     // 8 KiB wh2 row (MODE 3)

  const int gx = gridDim.x, gy = gridDim.y;
  int linb = blockIdx.x + gx * (blockIdx.y + gy * blockIdx.z);
  const int per = (gx * gy * gridDim.z) >> 3;
  int work = (linb & 7) * per + (linb >> 3);
  int bx, by, z;
  if constexpr (MODE == 0) {
    bx = work / gy;  // bx-major: each XCD sees ~1 B panel (L2-resident)
    by = work % gy;
    z = 0;
  } else {
    bx = work % gx;
    int tm = work / gx;
    by = tm % gy;
    z = tm / gy;  // one batch per XCD
  }

  Bm += (long)z * sB;
  const long zr0 = (long)z * NN;

  const int tid = threadIdx.x;
  const int m0 = by * 256;
  const int n0 = bx * 256;
  const int lane = tid & 63;
  const int wid = tid >> 6;
  const int wr = wid >> 2;  // 0..1  (M half)
  const int wc = wid & 3;   // 0..3  (N quarter)
  const int l15 = lane & 15;
  const int quad = lane >> 4;
  const int NT = K >> 6;
  const int cbase = (quad ^ (l15 & 7)) << 3;

  auto stageB_ = [&](int kt, int h) {
    const short* src = Bm + (long)(n0 + h * 128) * ldb + kt * 64;
    short* dst = &Bs[kt & 1][h * 8192];
#pragma unroll
    for (int it = 0; it < 2; ++it) {
      int r = it * 64 + (tid >> 3);
      int s = tid & 7;
      cp16(src + (long)r * ldb + ((s ^ (r & 7)) << 3),
           dst + (it * 512 + tid) * 8);
    }
  };

  // ---- generation state ----
  short8v gA0, gA1, gBh[4], gBl[4];
  const short* pbT = nullptr;
  unsigned mk = 0;
  float wh1v = 0.f, mrv = 0.f;
  const int gr = tid >> 1, gkh = tid & 1;  // MODE3 gen mapping

  auto genA_mfma = [&]() {  // MODE 0: expand P16·TW -> ELU -> At
#pragma unroll
    for (int f = 0; f < 2; ++f) {
      short8v Af = f ? gA1 : gA0;
#pragma unroll
      for (int cg = 0; cg < 4; ++cg) {
        f32x4 e = __builtin_amdgcn_mfma_f32_16x16x32_bf16(
            Af, gBh[cg], (f32x4){0.f, 0.f, 0.f, 0.f}, 0, 0, 0);
        e = __builtin_amdgcn_mfma_f32_16x16x32_bf16(Af, gBl[cg], e, 0, 0, 0);
#pragma unroll
        for (int reg = 0; reg < 4; ++reg) {
          float v = e[reg];
          v = v > 0.f ? v : (__expf(v) - 1.f);
          int row = wid * 32 + f * 16 + quad * 4 + reg;
          int c = cg * 16 + l15;
          At[row * 64 + (((c >> 3) ^ (row & 7)) << 3) + (c & 7)] = f2bf(v);
        }
      }
    }
  };

  auto genA_exp = [&](int kt1) {  // MODE 3: masked exp row values -> At
    const float4* wp = (const float4*)(whl + kt1 * 64 + gkh * 32);
    float wv[32];
#pragma unroll
    for (int cc = 0; cc < 8; ++cc) {
      float4 q = wp[cc];
      wv[cc * 4 + 0] = q.x; wv[cc * 4 + 1] = q.y;
      wv[cc * 4 + 2] = q.z; wv[cc * 4 + 3] = q.w;
    }
#pragma unroll
    for (int c = 0; c < 4; ++c) {
      short8v o;
#pragma unroll
      for (int e = 0; e < 8; ++e) {
        int j = c * 8 + e;
        float s = wh1v + wv[j];
        float l = fmaxf(s, ALPHA * s);
        float ex = __expf(l - mrv);
        o[e] = ((mk >> j) & 1u) ? f2bf(ex) : (short)0;
      }
      *(short8v*)(At + gr * 64 + ((((gkh << 2) + c) ^ (gr & 7)) << 3)) = o;
    }
  };

  f32x4 acc[8][4];
#pragma unroll
  for (int i = 0; i < 8; ++i)
#pragma unroll
    for (int j = 0; j < 4; ++j) acc[i][j] = (f32x4){0.f, 0.f, 0.f, 0.f};

  // ---- prologue: B(0) stage, gen(0) operands, gen(0) ----
  stageB_(0, 0);
  stageB_(0, 1);
  if constexpr (MODE == 0) {
    const short* pa = P2 + (((long)(m0 + wid * 32 + l15)) << 5) + quad * 8;
    gA0 = *(const short8v*)pa;
    gA1 = *(const short8v*)(pa + 512);
    pbT = TWb + (((long)l15) << 6) + quad * 8;
#pragma unroll
    for (int cg = 0; cg < 4; ++cg) {
      gBh[cg] = *(const short8v*)(pbT + (cg << 10));
      gBl[cg] = *(const short8v*)(pbT + (cg << 10) + 32);
    }
  } else {
    ((float4*)whl)[tid] = ((const float4*)(Wh2r + zr0))[tid];
    wh1v = Wh1r[zr0 + m0 + gr];
    mrv = mrow[zr0 + m0 + gr];
    mk = *(const unsigned*)((const char*)packed +
                            ((long)(zr0 + m0 + gr)) * 256 + gkh * 4);
  }
  asm volatile("s_waitcnt vmcnt(0)" ::: "memory");
  asm volatile("s_waitcnt lgkmcnt(0)" ::: "memory");
  SBAR();
  if constexpr (MODE == 0) genA_mfma(); else genA_exp(0);
  asm volatile("s_waitcnt lgkmcnt(0)" ::: "memory");
  SBAR();

#pragma unroll 1
  for (int t = 0; t < NT; ++t) {
    const int p = t & 1;
    const short* Ab = At;
    const short* Bb = Bs[p];
    short8v a[4][2], b0[2][2], b1[2][2];

    // ---- q0: issue B(t+1); read A(qm=0) + B(qn=0); MFMA Q00 ----
    if (t + 1 < NT) { stageB_(t + 1, 0); stageB_(t + 1, 1); }
#pragma unroll
    for (int ii = 0; ii < 4; ++ii) {
      int ro = (wr * 128 + ii * 16 + l15) * 64;
      a[ii][0] = *(const short8v*)(Ab + ro + cbase);
      a[ii][1] = *(const short8v*)(Ab + ro + (cbase ^ 32));
    }
#pragma unroll
    for (int jj = 0; jj < 2; ++jj) {
      int ro = (wc * 64 + jj * 16 + l15) * 64;
      b0[jj][0] = *(const short8v*)(Bb + ro + cbase);
      b0[jj][1] = *(const short8v*)(Bb + ro + (cbase ^ 32));
    }
    SBAR();
    asm volatile("s_waitcnt lgkmcnt(0)" ::: "memory");
    __builtin_amdgcn_sched_barrier(0);
    __builtin_amdgcn_s_setprio(1);
#pragma unroll
    for (int ii = 0; ii < 4; ++ii)
#pragma unroll
      for (int jj = 0; jj < 2; ++jj) {
        acc[ii][jj] = __builtin_amdgcn_mfma_f32_16x16x32_bf16(
            a[ii][0], b0[jj][0], acc[ii][jj], 0, 0, 0);
        acc[ii][jj] = __builtin_amdgcn_mfma_f32_16x16x32_bf16(
            a[ii][1], b0[jj][1], acc[ii][jj], 0, 0, 0);
      }
    __builtin_amdgcn_sched_barrier(0);
    __builtin_amdgcn_s_setprio(0);
    SBAR();

    // ---- q1: read B(qn=1); MFMA Q01 ----
#pragma unroll
    for (int jj = 0; jj < 2; ++jj) {
      int ro = (wc * 64 + 32 + jj * 16 + l15) * 64;
      b1[jj][0] = *(const short8v*)(Bb + ro + cbase);
      b1[jj][1] = *(const short8v*)(Bb + ro + (cbase ^ 32));
    }
    SBAR();
    asm volatile("s_waitcnt lgkmcnt(0)" ::: "memory");
    __builtin_amdgcn_sched_barrier(0);
    __builtin_amdgcn_s_setprio(1);
#pragma unroll
    for (int ii = 0; ii < 4; ++ii)
#pragma unroll
      for (int jj = 0; jj < 2; ++jj) {
        acc[ii][2 + jj] = __builtin_amdgcn_mfma_f32_16x16x32_bf16(
            a[ii][0], b1[jj][0], acc[ii][2 + jj], 0, 0, 0);
        acc[ii][2 + jj] = __builtin_amdgcn_mfma_f32_16x16x32_bf16(
            a[ii][1], b1[jj][1], acc[ii][2 + jj], 0, 0, 0);
      }
    __builtin_amdgcn_sched_barrier(0);
    __builtin_amdgcn_s_setprio(0);
    SBAR();

    // ---- q2: issue gen A-operand loads (t+1); read A(qm=1); MFMA Q11 ----
    if (t + 1 < NT) {
      if constexpr (MODE == 0) {
        int kt1 = t + 1, h1 = kt1 / 12;
        const short* pa =
            P2 + (((long)h1 * 16384 + m0 + wid * 32 + l15) << 5) + quad * 8;
        gA0 = *(const short8v*)pa;
        gA1 = *(const short8v*)(pa + 512);
        pbT = TWb + (((long)(kt1 * 64 + l15)) << 6) + quad * 8;
      } else {
        mk = *(const unsigned*)((const char*)packed +
                                ((long)(zr0 + m0 + gr)) * 256 + (t + 1) * 8 +
                                gkh * 4);
      }
    }
#pragma unroll
    for (int ii = 0; ii < 4; ++ii) {
      int ro = (wr * 128 + 64 + ii * 16 + l15) * 64;
      a[ii][0] = *(const short8v*)(Ab + ro + cbase);
      a[ii][1] = *(const short8v*)(Ab + ro + (cbase ^ 32));
    }
    SBAR();
    asm volatile("s_waitcnt lgkmcnt(0)" ::: "memory");
    __builtin_amdgcn_sched_barrier(0);
    __builtin_amdgcn_s_setprio(1);
#pragma unroll
    for (int ii = 0; ii < 4; ++ii)
#pragma unroll
      for (int jj = 0; jj < 2; ++jj) {
        acc[4 + ii][2 + jj] = __builtin_amdgcn_mfma_f32_16x16x32_bf16(
            a[ii][0], b1[jj][0], acc[4 + ii][2 + jj], 0, 0, 0);
        acc[4 + ii][2 + jj] = __builtin_amdgcn_mfma_f32_16x16x32_bf16(
            a[ii][1], b1[jj][1], acc[4 + ii][2 + jj], 0, 0, 0);
      }
    __builtin_amdgcn_sched_barrier(0);
    __builtin_amdgcn_s_setprio(0);
    SBAR();

    // ---- q3: issue TWb loads; MFMA Q10; drain; generate A(t+1) ----
    if (t + 1 < NT) {
      if constexpr (MODE == 0) {
#pragma unroll
        for (int cg = 0; cg < 4; ++cg) {
          gBh[cg] = *(const short8v*)(pbT + (cg << 10));
          gBl[cg] = *(const short8v*)(pbT + (cg << 10) + 32);
        }
      }
    }
    __builtin_amdgcn_s_setprio(1);
#pragma unroll
    for (int ii = 0; ii < 4; ++ii)
#pragma unroll
      for (int jj = 0; jj < 2; ++jj) {
        acc[4 + ii][jj] = __builtin_amdgcn_mfma_f32_16x16x32_bf16(
            a[ii][0], b0[jj][0], acc[4 + ii][jj], 0, 0, 0);
        acc[4 + ii][jj] = __builtin_amdgcn_mfma_f32_16x16x32_bf16(
            a[ii][1], b0[jj][1], acc[4 + ii][jj], 0, 0, 0);
      }
    __builtin_amdgcn_sched_barrier(0);
    __builtin_amdgcn_s_setprio(0);
    if (t + 1 < NT) {
      asm volatile("s_waitcnt vmcnt(0)" ::: "memory");
      if constexpr (MODE == 0) genA_mfma(); else genA_exp(t + 1);
      asm volatile("s_waitcnt lgkmcnt(0)" ::: "memory");
    }
    SBAR();
  }

  // ---- epilogues (C/D layout: col=l15, row=quad*4+reg per 16x16 frag) ----
  if constexpr (MODE == 3) {
    float ivv[8][4];
#pragma unroll
    for (int mi = 0; mi < 8; ++mi)
#pragma unroll
      for (int reg = 0; reg < 4; ++reg)
        ivv[mi][reg] =
            invs[zr0 + m0 + wr * 128 + mi * 16 + quad * 4 + reg];
#pragma unroll
    for (int nj = 0; nj < 4; ++nj) {
      int col = n0 + wc * 64 + nj * 16 + l15;
      float s = 0.f;
#pragma unroll
      for (int mi = 0; mi < 8; ++mi)
#pragma unroll
        for (int reg = 0; reg < 4; ++reg) {
          float v = acc[mi][nj][reg] * ivv[mi][reg];
          s += v > 0.f ? v : (__expf(v) - 1.f);
        }
      s += __shfl_xor(s, 16);
      s += __shfl_xor(s, 32);
      if (quad == 0) atomicAdd(Cf + (long)z * HID + col, s * (1.0f / NN));
    }
  } else {  // MODE 0: a-dot atomics + direct transposed Ct store
    float a1v[4], a2v[4];
#pragma unroll
    for (int nj = 0; nj < 4; ++nj) {
      int colh = n0 + wc * 64 + nj * 16 + l15;  // < 768
      a1v[nj] = a_vec[colh];
      a2v[nj] = a_vec[HID + colh];
    }
#pragma unroll
    for (int mi = 0; mi < 8; ++mi) {
      int rb = m0 + wr * 128 + mi * 16 + quad * 4;
#pragma unroll
      for (int reg = 0; reg < 4; ++reg) {
        float s1 = 0.f, s2 = 0.f;
#pragma unroll
        for (int nj = 0; nj < 4; ++nj) {
          s1 = fmaf(acc[mi][nj][reg], a1v[nj], s1);
          s2 = fmaf(acc[mi][nj][reg], a2v[nj], s2);
        }
#pragma unroll
        for (int off = 1; off < 16; off <<= 1) {
          s1 += __shfl_xor(s1, off);
          s2 += __shfl_xor(s2, off);
        }
        if (l15 == 0) {
          atomicAdd(Wh1g + rb + reg, s1);
          atomicAdd(Wh2g + rb + reg, s2);
        }
      }
    }
    const int bb = m0 >> 11;
    const int ml0 = (m0 & 2047) + wr * 128;
#pragma unroll
    for (int mi = 0; mi < 8; ++mi) {
#pragma unroll
      for (int nj = 0; nj < 4; ++nj) {
        int colh = n0 + wc * 64 + nj * 16 + l15;
        short4v pk;
#pragma unroll
        for (int reg = 0; reg < 4; ++reg) pk[reg] = f2bf(acc[mi][nj][reg]);
        *(short4v*)(Ct + ((long)bb * HID + colh) * NN + ml0 + mi * 16 +
                    quad * 4) = pk;
      }
    }
  }
}

// ---------------------------------------------------------------------------
// Layer-2 row softmax STATS (no att materialization): m[row], 1/sum[row].
// grid 16384. Blocks [0,zn) also zero zA (final output accumulator).
// ---------------------------------------------------------------------------
__global__ __launch_bounds__(256) void attn_stats_kernel(
    const float* __restrict__ Wh1, const float* __restrict__ Wh2,
    const unsigned long long* __restrict__ packed, float* __restrict__ mr,
    float* __restrict__ iv, float* __restrict__ zA, int zn) {
  int row = blockIdx.x;
  if (row < zn) zA[row * 256 + threadIdx.x] = 0.f;
  int b = row >> 11;
  const unsigned char* bits = (const unsigned char*)(packed + (long)row * 32);
  const float* wh2b = Wh2 + b * NN;
  const int t = threadIdx.x;
  const int lane = t & 63;
  const int wv = t >> 6;

  unsigned m8 = bits[t];
  float wh1 = Wh1[row];
  float4 wa = ((const float4*)(wh2b + t * 8))[0];
  float4 wb = ((const float4*)(wh2b + t * 8))[1];
  float v[8] = {wa.x, wa.y, wa.z, wa.w, wb.x, wb.y, wb.z, wb.w};

  float lmax = -INFINITY;
#pragma unroll
  for (int k = 0; k < 8; ++k) {
    float s = wh1 + v[k];
    s = s > 0.f ? s : ALPHA * s;
    s = ((m8 >> k) & 1u) ? s : NEGV;
    v[k] = s;
    lmax = fmaxf(lmax, s);
  }

  __shared__ float redm[4], reds[4];
#pragma unroll
  for (int off = 32; off > 0; off >>= 1) lmax = fmaxf(lmax, __shfl_xor(lmax, off));
  if (lane == 0) redm[wv] = lmax;
  __syncthreads();
  float m = fmaxf(fmaxf(redm[0], redm[1]), fmaxf(redm[2], redm[3]));

  float lsum = 0.f;
#pragma unroll
  for (int k = 0; k < 8; ++k) lsum += __expf(v[k] - m);
#pragma unroll
  for (int off = 32; off > 0; off >>= 1) lsum += __shfl_xor(lsum, off);
  if (lane == 0) reds[wv] = lsum;
  __syncthreads();
  if (t == 0) {
    mr[row] = m;
    iv[row] = 1.f / (reds[0] + reds[1] + reds[2] + reds[3]);
  }
}

// ---------------------------------------------------------------------------
extern "C" void kernel_launch(void* const* d_in, const int* in_sizes, int n_in,
                              void* d_out, int out_size, void* d_ws,
                              size_t ws_size, hipStream_t stream) {
  const int* node_feats = (const int*)d_in[0];
  const int* adjs = (const int*)d_in[1];
  const float* embed_table = (const float*)d_in[2];
  const float* W_heads = (const float*)d_in[3];
  const float* a_heads = (const float*)d_in[4];
  const float* W_out = (const float*)d_in[5];
  const float* a_out = (const float*)d_in[6];
  float* out = (float*)d_out;

  // workspace layout (~42 MB)
  char* p = (char*)d_ws;
  short* Wt_o = (short*)p;  p += (size_t)HID * (NHEADS * HID) * 2;       // 4.7 MB
  short* Wh_t = (short*)p;  p += (size_t)BB * HID * NN * 2;              // 25 MB
  short* P2 = (short*)p;    p += (size_t)NHEADS * 16384 * 32 * 2;        // 4 MB
  short* TWb = (short*)p;   p += (size_t)(NHEADS * HID) * 64 * 2;        // 384 KB
  unsigned long long* padj = (unsigned long long*)p;
  p += (size_t)BB * NN * NN / 8;                                         // 4.2 MB
  // zero region (ZERO_B*256 floats): Wh1, Wh2, TW1, TW2, mrow, invs, pad
  float* Wh1 = (float*)p;   p += (size_t)16384 * 4;
  float* Wh2 = (float*)p;   p += (size_t)16384 * 4;
  float* TW1 = (float*)p;   p += (size_t)64 * 4;
  float* TW2 = (float*)p;   p += (size_t)64 * 4;
  float* mrow = (float*)p;  p += (size_t)16384 * 4;
  float* invs = (float*)p;  p += (size_t)16384 * 4;
  p += (size_t)(ZERO_B * 256 - 4 * 16384 - 128) * 4;  // pad (zeroed)
  float* TWp = (float*)p;   p += (size_t)16 * VOCAB * NHEADS * HID * 4;  // 2.9 MB
  unsigned long long* nfm = (unsigned long long*)p;
  p += (size_t)BB * VOCAB * 32 * 8;                                      // 30 KB
  if ((size_t)(p - (char*)d_ws) > ws_size) return;

  // 0) mega-setup: adj pack + zeros + vocab masks + W_out transpose + TW
  setup_kernel<<<PACK_B + ZERO_B + NFM_B + TRAN_B + TW_B, 256, 0, stream>>>(
      adjs, padj, Wh1, node_feats, nfm, W_out, Wt_o, embed_table, W_heads,
      TWp);

  // 1) layer 1: TW reduce -> TWb + a-dots; popcount-P16 -> P2 hi/lo
  tw_finish_kernel<<<12, 256, 0, stream>>>(TWp, TWb, a_heads, TW1, TW2);
  p16_kernel<<<16384 / 4, 256, 0, stream>>>(
      node_feats, (const unsigned*)padj, (const unsigned*)nfm, TW1, TW2, P2);

  // 2) output GAT layer: fused expand-GEMM -> Wh_t + Wh1/Wh2 atomics
  mfma_gemm<0><<<dim3(HID / 256, MTOT / 256, 1), 512, 0, stream>>>(
      Wt_o, NHEADS * HID, NHEADS * HID, 0, P2, TWb, nullptr, nullptr, nullptr,
      nullptr, nullptr, nullptr, Wh_t, a_out, Wh1, Wh2);
  attn_stats_kernel<<<MTOT, 256, 0, stream>>>(Wh1, Wh2, padj, mrow, invs, out,
                                              24);
  mfma_gemm<3><<<dim3(HID / 256, NN / 256, BB), 512, 0, stream>>>(
      Wh_t, NN, NN, (long)HID * NN, nullptr, nullptr, Wh1, Wh2, padj, mrow,
      invs, out, nullptr, nullptr, nullptr, nullptr);
}

// Round 3
// 465.707 us; speedup vs baseline: 1.4228x; 1.4228x over previous
//
#include <hip/hip_runtime.h>
#include <math.h>

#define BB 8
#define NN 2048
#define HID 768
#define NHEADS 4
#define VOCAB 15
#define ALPHA 0.2f
#define NEGV -9e15f
#define MTOT (BB * NN)  // 16384

using short4v = __attribute__((ext_vector_type(4))) short;
using short8v = __attribute__((ext_vector_type(8))) short;
using f32x4 = __attribute__((ext_vector_type(4))) float;

__device__ __forceinline__ short f2bf(float f) {
  union { float f; unsigned u; } x;
  x.f = f;
  unsigned r = x.u + 0x7fffu + ((x.u >> 16) & 1u);
  return (short)(r >> 16);
}

__device__ __forceinline__ void cp16(const void* g, void* l) {
  __builtin_amdgcn_global_load_lds(
      (const __attribute__((address_space(1))) unsigned int*)g,
      (__attribute__((address_space(3))) unsigned int*)l, 16, 0, 0);
}

// pack 8 bytes' low nibbles (LE order) into 32 bits
__device__ __forceinline__ unsigned long long nibcompress(unsigned long long x) {
  x = (x | (x >> 4)) & 0x00FF00FF00FF00FFull;
  x = (x | (x >> 8)) & 0x0000FFFF0000FFFFull;
  x = (x | (x >> 16)) & 0x00000000FFFFFFFFull;
  return x;
}

#define MEMFENCE asm volatile("" ::: "memory")
#define SBAR()                         \
  do {                                 \
    MEMFENCE;                          \
    __builtin_amdgcn_s_barrier();      \
    MEMFENCE;                          \
  } while (0)

// ---------------------------------------------------------------------------
// Mega-setup: [0,PACK_B) adjacency bit-pack, int4-vectorized (1024/block);
// [+ZERO_B) zero {Wh1,Wh2,TW1,TW2,pad}; [+NFM_B) per-batch vocab bitmasks;
// [+TRAN_B) W_out transpose; [+TW_B) TW partials (per-ky disjoint slots).
// ---------------------------------------------------------------------------
#define PACK_B 32768
#define ZERO_B 308
#define NFM_B 64
#define TRAN_B 2304  // 96 x 24 tiles of 32x32
#define TW_B 192     // 12 col-chunks x 16 k-chunks
__global__ __launch_bounds__(256) void setup_kernel(
    const int* __restrict__ adj, unsigned long long* __restrict__ packed,
    float* __restrict__ zbase, const int* __restrict__ nf,
    unsigned long long* __restrict__ nfm, const float* __restrict__ W_out,
    short* __restrict__ Wt_o, const float* __restrict__ table,
    const float* __restrict__ W_heads, float* __restrict__ TWp) {
  const int bid = blockIdx.x;
  const int tid = threadIdx.x;
  if (bid < PACK_B) {
    __shared__ unsigned long long nibq[32];
    long base = (long)bid * 1024;
    int4 a = *(const int4*)(adj + base + tid * 4);
    unsigned nib = (a.x > 0 ? 1u : 0u) | (a.y > 0 ? 2u : 0u) |
                   (a.z > 0 ? 4u : 0u) | (a.w > 0 ? 8u : 0u);
    ((unsigned char*)nibq)[tid] = (unsigned char)nib;
    __syncthreads();
    if (tid < 16) {
      unsigned long long lo = nibcompress(nibq[2 * tid]);
      unsigned long long hi = nibcompress(nibq[2 * tid + 1]);
      packed[(base >> 6) + tid] = lo | (hi << 32);
    }
  } else if (bid < PACK_B + ZERO_B) {
    zbase[(bid - PACK_B) * 256 + tid] = 0.f;
  } else if (bid < PACK_B + ZERO_B + NFM_B) {
    int r = bid - PACK_B - ZERO_B;  // 0..63
    int b = r >> 3, c = r & 7;
    int w = tid >> 6;
    int j = c * 256 + tid;
    int nfv = nf[b * NN + j];
#pragma unroll
    for (int v = 0; v < VOCAB; ++v) {
      unsigned long long m = __ballot(nfv == v);
      if ((tid & 63) == 0) nfm[((long)b * VOCAB + v) * 32 + c * 4 + w] = m;
    }
  } else if (bid < PACK_B + ZERO_B + NFM_B + TRAN_B) {
    // W_out transpose (3072x768 -> bf16 768x3072)
    __shared__ float t[32][33];
    int r2 = bid - PACK_B - ZERO_B - NFM_B;
    const int K = NHEADS * HID, N = HID;
    int k0 = (r2 % 96) * 32, n0 = (r2 / 96) * 32;
    int tx = tid & 31, ty = tid >> 5;
#pragma unroll
    for (int i = 0; i < 32; i += 8)
      t[ty + i][tx] = W_out[(long)(k0 + ty + i) * N + n0 + tx];
    __syncthreads();
#pragma unroll
    for (int i = 0; i < 32; i += 8)
      Wt_o[(long)(n0 + ty + i) * K + k0 + tx] = f2bf(t[tx][ty + i]);
  } else {
    // TW partial: col-chunk cx (256 cols), k-chunk ky (48 k) -> disjoint slot
    __shared__ float tbl[VOCAB][48];
    int r3 = bid - PACK_B - ZERO_B - NFM_B - TRAN_B;  // 0..191
    const int cx = r3 % 12, ky = r3 / 12;
    const int c = cx * 256 + tid;
    const int h = (cx * 256) / HID;
    const int n = c - h * HID;
    const int k0 = ky * 48;
    for (int idx = tid; idx < VOCAB * 48; idx += 256)
      tbl[idx / 48][idx % 48] = table[(idx / 48) * HID + k0 + idx % 48];
    __syncthreads();
    float acc[VOCAB];
#pragma unroll
    for (int v = 0; v < VOCAB; ++v) acc[v] = 0.f;
    const float* wp = W_heads + (long)h * HID * HID + (long)k0 * HID + n;
#pragma unroll 8
    for (int kk = 0; kk < 48; ++kk) {
      float w = wp[(long)kk * HID];
#pragma unroll
      for (int v = 0; v < VOCAB; ++v) acc[v] = fmaf(tbl[v][kk], w, acc[v]);
    }
#pragma unroll
    for (int v = 0; v < VOCAB; ++v)
      TWp[((long)ky * VOCAB + v) * (NHEADS * HID) + c] = acc[v];
  }
}

// ---------------------------------------------------------------------------
// Fused: reduce 16 TW partials -> TW, and accumulate a-dot partials into
// TW1/TW2 (zeroed by setup) via per-block reduce + atomicAdd. grid 12.
// ---------------------------------------------------------------------------
__global__ __launch_bounds__(256) void tw_finish_kernel(
    const float* __restrict__ TWp, float* __restrict__ TW,
    const float* __restrict__ a_heads, float* __restrict__ TW1,
    float* __restrict__ TW2) {
  const int tid = threadIdx.x;
  const int c = blockIdx.x * 256 + tid;  // 0..3071
  const int h = (blockIdx.x * 256) / HID;  // uniform per block
  const int n = c - h * HID;
  const float a1 = a_heads[h * 2 * HID + n];
  const float a2 = a_heads[h * 2 * HID + HID + n];
  const int lane = tid & 63;
  const int wv = tid >> 6;
  __shared__ float red[4][2 * VOCAB];

  float s1[VOCAB], s2[VOCAB];
#pragma unroll
  for (int v = 0; v < VOCAB; ++v) {
    float s = 0.f;
#pragma unroll
    for (int ky = 0; ky < 16; ++ky)
      s += TWp[((long)ky * VOCAB + v) * (NHEADS * HID) + c];
    TW[v * (NHEADS * HID) + c] = s;
    s1[v] = s * a1;
    s2[v] = s * a2;
  }
#pragma unroll
  for (int off = 1; off < 64; off <<= 1)
#pragma unroll
    for (int v = 0; v < VOCAB; ++v) {
      s1[v] += __shfl_xor(s1[v], off);
      s2[v] += __shfl_xor(s2[v], off);
    }
  if (lane == 0) {
#pragma unroll
    for (int v = 0; v < VOCAB; ++v) {
      red[wv][v] = s1[v];
      red[wv][VOCAB + v] = s2[v];
    }
  }
  __syncthreads();
  if (tid < 2 * VOCAB) {
    float s = red[0][tid] + red[1][tid] + red[2][tid] + red[3][tid];
    float* dst = (tid < VOCAB) ? (TW1 + h * VOCAB + tid)
                               : (TW2 + h * VOCAB + tid - VOCAB);
    atomicAdd(dst, s);
  }
}

// ---------------------------------------------------------------------------
// P16 via popcount: one wave per row; 15-value softmax for all 4 heads.
// ---------------------------------------------------------------------------
__global__ __launch_bounds__(256) void p16_kernel(
    const int* __restrict__ nf, const unsigned* __restrict__ padj32,
    const unsigned* __restrict__ nfm32, const float* __restrict__ TW1,
    const float* __restrict__ TW2, float* __restrict__ P16) {
  const int t = threadIdx.x;
  const int wv = t >> 6;
  const int lane = t & 63;
  const int rowm = blockIdx.x * 4 + wv;
  const int b = rowm >> 11;
  __shared__ float cnts[4][16];

  unsigned a = padj32[(long)rowm * 64 + lane];
  const unsigned* nb = nfm32 + (long)b * VOCAB * 64 + lane;
  int cnt[VOCAB];
#pragma unroll
  for (int v = 0; v < VOCAB; ++v) cnt[v] = __popc(a & nb[v * 64]);
#pragma unroll
  for (int off = 1; off < 64; off <<= 1)
#pragma unroll
    for (int v = 0; v < VOCAB; ++v) cnt[v] += __shfl_xor(cnt[v], off);
  int cntsum = 0;
#pragma unroll
  for (int v = 0; v < VOCAB; ++v) cntsum += cnt[v];
  const bool use_full = (cntsum == 0);  // wave-uniform
  if (use_full) {
#pragma unroll
    for (int v = 0; v < VOCAB; ++v) cnt[v] = __popc(nb[v * 64]);
#pragma unroll
    for (int off = 1; off < 64; off <<= 1)
#pragma unroll
      for (int v = 0; v < VOCAB; ++v) cnt[v] += __shfl_xor(cnt[v], off);
  }
  if (lane < 16) cnts[wv][lane] = (lane < VOCAB) ? (float)cnt[lane] : 0.f;
  __syncthreads();

  const int h = lane >> 4;
  const int v = lane & 15;
  const int nfi = nf[b * NN + (rowm & 2047)];
  float cvf = cnts[wv][v];
  bool valid = (v < VOCAB) && (cvf > 0.f);
  float logit = 0.f;
  if (!use_full) {
    float s = TW1[h * VOCAB + nfi] + ((v < VOCAB) ? TW2[h * VOCAB + v] : 0.f);
    logit = s > 0.f ? s : ALPHA * s;
  }
  float mv = valid ? logit : -INFINITY;
#pragma unroll
  for (int off = 1; off < 16; off <<= 1) mv = fmaxf(mv, __shfl_xor(mv, off));
  float pv = valid ? cvf * __expf(logit - mv) : 0.f;
  float sum = pv;
#pragma unroll
  for (int off = 1; off < 16; off <<= 1) sum += __shfl_xor(sum, off);
  if (v < VOCAB) P16[((long)h * 16384 + rowm) * 16 + v] = pv / sum;
}

// ---------------------------------------------------------------------------
// hcat[r][h*HID+colh] = ELU( sum_v P16[h][r][v] * TW[v][h*HID+colh] ) -> bf16
// ---------------------------------------------------------------------------
__global__ __launch_bounds__(256) void hcat_expand(
    const float* __restrict__ TW, const float* __restrict__ P16,
    short* __restrict__ hcat) {
  __shared__ float twl[VOCAB * 128];
  __shared__ float pl[128 * 16];
  const int c0 = blockIdx.x * 128;
  const int r0 = blockIdx.y * 128;
  const int h = c0 / HID;
  const int t = threadIdx.x;
  for (int idx = t; idx < VOCAB * 128; idx += 256)
    twl[idx] = TW[(idx / 128) * (NHEADS * HID) + c0 + (idx & 127)];
  for (int idx = t; idx < 128 * 16; idx += 256)
    pl[idx] = P16[((long)h * 16384 + r0 + (idx >> 4)) * 16 + (idx & 15)];
  __syncthreads();
  const int clb = (t & 31) * 4;
  const int rlb = (t >> 5) * 16;
#pragma unroll 4
  for (int rr = 0; rr < 16; ++rr) {
    int rl = rlb + rr;
    short4v o;
#pragma unroll
    for (int cc = 0; cc < 4; ++cc) {
      float s = 0.f;
#pragma unroll
      for (int vv = 0; vv < VOCAB; ++vv)
        s = fmaf(pl[rl * 16 + vv], twl[vv * 128 + clb + cc], s);
      s = s > 0.f ? s : (__expf(s) - 1.f);
      o[cc] = f2bf(s);
    }
    *(short4v*)(hcat + (long)(r0 + rl) * (NHEADS * HID) + c0 + clb) = o;
  }
}

// ---------------------------------------------------------------------------
// bf16 MFMA GEMM, 256x192 tile, BK=64, 512 threads (8 waves, 2Mx4N);
// exact-coverage grids (256 blocks = 1/CU). 4 phases/K-tile, counted
// vmcnt(4) (A=4 loads, B=3 loads per thread), K-chunk XOR swizzle via
// pre-swizzled global source + swizzled ds_read. A,B double-buffered
// (112 KiB LDS).
//   Ledger (tile t): B(t+1) issued at t.q0; A(t+2) issued at t.q3;
//   t.q3 vmcnt(4) drains A(t+1)+B(t+1), keeps A(t+2) in flight.
// MODE 0: a-dot atomics + transposed bf16 Ct [bb][colh][row] (layer 2).
// MODE 3: fused ELU + mean-pool: atomicAdd Cf[z*HID + col].
// ---------------------------------------------------------------------------
template <int MODE>
__global__ __launch_bounds__(512, 2) void mfma_gemm(
    const short* __restrict__ A, const short* __restrict__ B,
    int K, int lda, int ldb, long sA, long sB,
    float* __restrict__ Cf, short* __restrict__ Ct,
    const float* __restrict__ a_vec, float* __restrict__ Wh1g,
    float* __restrict__ Wh2g) {
  __shared__ short As[2][16384];  // 64 KiB: 256 rows x 64 k, dbuf
  __shared__ short Bs[2][12288];  // 48 KiB: 192 rows x 64 k, dbuf

  const int gx = gridDim.x, gy = gridDim.y;
  int linb = blockIdx.x + gx * (blockIdx.y + gy * blockIdx.z);
  const int per = (gx * gy * gridDim.z) >> 3;
  int work = (linb & 7) * per + (linb >> 3);
  int bx, by, z;
  if constexpr (MODE == 0) {
    bx = work / gy;  // bx-major: each XCD works within ~1 B panel (L2-res)
    by = work % gy;
    z = 0;
  } else {
    bx = work % gx;
    int tm = work / gx;
    by = tm % gy;
    z = tm / gy;  // one batch per XCD: B panel (3.1 MB) L2-resident
  }

  A += (long)z * sA;
  B += (long)z * sB;

  const int tid = threadIdx.x;
  const int m0 = by * 256;
  const int n0 = bx * 192;
  const int lane = tid & 63;
  const int wid = tid >> 6;
  const int wr = wid >> 2;  // 0..1  (M half, 128 rows)
  const int wc = wid & 3;   // 0..3  (N quarter, 48 cols)
  const int l15 = lane & 15;
  const int quad = lane >> 4;
  const int NT = K >> 6;
  const int cbase = (quad ^ (l15 & 7)) << 3;

  auto stageA = [&](int kt) {  // 4 cp16/thread
    const short* src = A + (long)m0 * lda + kt * 64;
    short* dst = As[kt & 1];
#pragma unroll
    for (int it = 0; it < 4; ++it) {
      int r = it * 64 + (tid >> 3);
      int s = tid & 7;
      cp16(src + (long)r * lda + ((s ^ (r & 7)) << 3),
           dst + (it * 512 + tid) * 8);
    }
  };
  auto stageB = [&](int kt) {  // 3 cp16/thread
    const short* src = B + (long)n0 * ldb + kt * 64;
    short* dst = Bs[kt & 1];
#pragma unroll
    for (int it = 0; it < 3; ++it) {
      int r = it * 64 + (tid >> 3);
      int s = tid & 7;
      cp16(src + (long)r * ldb + ((s ^ (r & 7)) << 3),
           dst + (it * 512 + tid) * 8);
    }
  };

  f32x4 acc[8][3];
#pragma unroll
  for (int i = 0; i < 8; ++i)
#pragma unroll
    for (int j = 0; j < 3; ++j) acc[i][j] = (f32x4){0.f, 0.f, 0.f, 0.f};

  // prologue: tile0 fully, tile1's A (kept in flight across the wait)
  stageB(0);
  stageA(0);
  stageA(1);
  asm volatile("s_waitcnt vmcnt(4)" ::: "memory");
  SBAR();

#pragma unroll 1
  for (int t = 0; t < NT; ++t) {
    const int p = t & 1;
    const short* Ab = As[p];
    const short* Bb = Bs[p];
    short8v a[4][2], b0[2][2], b1[2];

    // ---- q0: issue B(t+1); read A(ii0..3) + B(nj0..1); MFMA Q00 (16) ----
    if (t + 1 < NT) stageB(t + 1);
#pragma unroll
    for (int ii = 0; ii < 4; ++ii) {
      int ro = (wr * 128 + ii * 16 + l15) * 64;
      a[ii][0] = *(const short8v*)(Ab + ro + cbase);
      a[ii][1] = *(const short8v*)(Ab + ro + (cbase ^ 32));
    }
#pragma unroll
    for (int jj = 0; jj < 2; ++jj) {
      int ro = (wc * 48 + jj * 16 + l15) * 64;
      b0[jj][0] = *(const short8v*)(Bb + ro + cbase);
      b0[jj][1] = *(const short8v*)(Bb + ro + (cbase ^ 32));
    }
    SBAR();
    asm volatile("s_waitcnt lgkmcnt(0)" ::: "memory");
    __builtin_amdgcn_sched_barrier(0);
    __builtin_amdgcn_s_setprio(1);
#pragma unroll
    for (int ii = 0; ii < 4; ++ii)
#pragma unroll
      for (int jj = 0; jj < 2; ++jj) {
        acc[ii][jj] = __builtin_amdgcn_mfma_f32_16x16x32_bf16(
            a[ii][0], b0[jj][0], acc[ii][jj], 0, 0, 0);
        acc[ii][jj] = __builtin_amdgcn_mfma_f32_16x16x32_bf16(
            a[ii][1], b0[jj][1], acc[ii][jj], 0, 0, 0);
      }
    __builtin_amdgcn_sched_barrier(0);
    __builtin_amdgcn_s_setprio(0);
    SBAR();

    // ---- q1: read B(nj=2); MFMA Q01 (8) ----
    {
      int ro = (wc * 48 + 32 + l15) * 64;
      b1[0] = *(const short8v*)(Bb + ro + cbase);
      b1[1] = *(const short8v*)(Bb + ro + (cbase ^ 32));
    }
    SBAR();
    asm volatile("s_waitcnt lgkmcnt(0)" ::: "memory");
    __builtin_amdgcn_sched_barrier(0);
    __builtin_amdgcn_s_setprio(1);
#pragma unroll
    for (int ii = 0; ii < 4; ++ii) {
      acc[ii][2] = __builtin_amdgcn_mfma_f32_16x16x32_bf16(
          a[ii][0], b1[0], acc[ii][2], 0, 0, 0);
      acc[ii][2] = __builtin_amdgcn_mfma_f32_16x16x32_bf16(
          a[ii][1], b1[1], acc[ii][2], 0, 0, 0);
    }
    __builtin_amdgcn_sched_barrier(0);
    __builtin_amdgcn_s_setprio(0);
    SBAR();

    // ---- q2: read A(ii4..7); MFMA Q12 (8) ----
#pragma unroll
    for (int ii = 0; ii < 4; ++ii) {
      int ro = (wr * 128 + 64 + ii * 16 + l15) * 64;
      a[ii][0] = *(const short8v*)(Ab + ro + cbase);
      a[ii][1] = *(const short8v*)(Ab + ro + (cbase ^ 32));
    }
    SBAR();
    asm volatile("s_waitcnt lgkmcnt(0)" ::: "memory");
    __builtin_amdgcn_sched_barrier(0);
    __builtin_amdgcn_s_setprio(1);
#pragma unroll
    for (int ii = 0; ii < 4; ++ii) {
      acc[4 + ii][2] = __builtin_amdgcn_mfma_f32_16x16x32_bf16(
          a[ii][0], b1[0], acc[4 + ii][2], 0, 0, 0);
      acc[4 + ii][2] = __builtin_amdgcn_mfma_f32_16x16x32_bf16(
          a[ii][1], b1[1], acc[4 + ii][2], 0, 0, 0);
    }
    __builtin_amdgcn_sched_barrier(0);
    __builtin_amdgcn_s_setprio(0);
    SBAR();

    // ---- q3: issue A(t+2) (buf p dead: q2 barrier passed); MFMA Q10 (16);
    //          counted vmcnt keeps A(t+2) in flight ----
    if (t + 2 < NT) stageA(t + 2);
    __builtin_amdgcn_s_setprio(1);
#pragma unroll
    for (int ii = 0; ii < 4; ++ii)
#pragma unroll
      for (int jj = 0; jj < 2; ++jj) {
        acc[4 + ii][jj] = __builtin_amdgcn_mfma_f32_16x16x32_bf16(
            a[ii][0], b0[jj][0], acc[4 + ii][jj], 0, 0, 0);
        acc[4 + ii][jj] = __builtin_amdgcn_mfma_f32_16x16x32_bf16(
            a[ii][1], b0[jj][1], acc[4 + ii][jj], 0, 0, 0);
      }
    __builtin_amdgcn_sched_barrier(0);
    __builtin_amdgcn_s_setprio(0);
    if (t + 2 < NT) {
      asm volatile("s_waitcnt vmcnt(4)" ::: "memory");
    } else if (t + 1 < NT) {
      asm volatile("s_waitcnt vmcnt(0)" ::: "memory");
    }
    SBAR();
  }

  // ---- epilogues (C/D layout: col=l15, row=quad*4+reg per 16x16 frag;
  //      acc[mi][nj] covers rows wr*128+mi*16, cols wc*48+nj*16) ----
  if constexpr (MODE == 3) {
#pragma unroll
    for (int nj = 0; nj < 3; ++nj) {
      int col = n0 + wc * 48 + nj * 16 + l15;
      float s = 0.f;
#pragma unroll
      for (int mi = 0; mi < 8; ++mi)
#pragma unroll
        for (int reg = 0; reg < 4; ++reg) {
          float v = acc[mi][nj][reg];
          s += v > 0.f ? v : (__expf(v) - 1.f);
        }
      s += __shfl_xor(s, 16);
      s += __shfl_xor(s, 32);
      if (quad == 0) atomicAdd(Cf + (long)z * HID + col, s * (1.0f / NN));
    }
  } else {  // MODE 0: a-dot atomics + direct transposed Ct store
    float a1v[3], a2v[3];
#pragma unroll
    for (int nj = 0; nj < 3; ++nj) {
      int colh = n0 + wc * 48 + nj * 16 + l15;  // < 768
      a1v[nj] = a_vec[colh];
      a2v[nj] = a_vec[HID + colh];
    }
#pragma unroll
    for (int mi = 0; mi < 8; ++mi) {
      int rb = m0 + wr * 128 + mi * 16 + quad * 4;
#pragma unroll
      for (int reg = 0; reg < 4; ++reg) {
        float s1 = 0.f, s2 = 0.f;
#pragma unroll
        for (int nj = 0; nj < 3; ++nj) {
          s1 = fmaf(acc[mi][nj][reg], a1v[nj], s1);
          s2 = fmaf(acc[mi][nj][reg], a2v[nj], s2);
        }
#pragma unroll
        for (int off = 1; off < 16; off <<= 1) {
          s1 += __shfl_xor(s1, off);
          s2 += __shfl_xor(s2, off);
        }
        if (l15 == 0) {
          atomicAdd(Wh1g + rb + reg, s1);
          atomicAdd(Wh2g + rb + reg, s2);
        }
      }
    }
    const int bb = m0 >> 11;
    const int ml0 = (m0 & 2047) + wr * 128;
#pragma unroll
    for (int mi = 0; mi < 8; ++mi) {
#pragma unroll
      for (int nj = 0; nj < 3; ++nj) {
        int colh = n0 + wc * 48 + nj * 16 + l15;
        short4v pk;
#pragma unroll
        for (int reg = 0; reg < 4; ++reg) pk[reg] = f2bf(acc[mi][nj][reg]);
        *(short4v*)(Ct + ((long)bb * HID + colh) * NN + ml0 + mi * 16 +
                    quad * 4) = pk;
      }
    }
  }
}

// ---------------------------------------------------------------------------
// Layer-2 row softmax (materializing, bf16 att). grid 16384. Blocks [0,zn)
// also zero zA (final output accumulator; write-disjoint from reads).
// ---------------------------------------------------------------------------
__global__ __launch_bounds__(256) void attn_softmax_kernel(
    const float* __restrict__ Wh1, const float* __restrict__ Wh2,
    const unsigned long long* __restrict__ packed, short* __restrict__ att,
    float* __restrict__ zA, int zn) {
  int row = blockIdx.x;
  if (row < zn) zA[row * 256 + threadIdx.x] = 0.f;
  int b = row >> 11;
  const unsigned char* bits = (const unsigned char*)(packed + (long)row * 32);
  const float* wh2b = Wh2 + b * NN;
  const int t = threadIdx.x;
  const int lane = t & 63;
  const int wv = t >> 6;

  unsigned m8 = bits[t];
  float wh1 = Wh1[row];
  float4 wa = ((const float4*)(wh2b + t * 8))[0];
  float4 wb = ((const float4*)(wh2b + t * 8))[1];
  float v[8] = {wa.x, wa.y, wa.z, wa.w, wb.x, wb.y, wb.z, wb.w};

  float lmax = -INFINITY;
#pragma unroll
  for (int k = 0; k < 8; ++k) {
    float s = wh1 + v[k];
    s = s > 0.f ? s : ALPHA * s;
    s = ((m8 >> k) & 1u) ? s : NEGV;
    v[k] = s;
    lmax = fmaxf(lmax, s);
  }

  __shared__ float redm[4], reds[4];
#pragma unroll
  for (int off = 32; off > 0; off >>= 1) lmax = fmaxf(lmax, __shfl_xor(lmax, off));
  if (lane == 0) redm[wv] = lmax;
  __syncthreads();
  float m = fmaxf(fmaxf(redm[0], redm[1]), fmaxf(redm[2], redm[3]));

  float lsum = 0.f;
#pragma unroll
  for (int k = 0; k < 8; ++k) {
    float p = __expf(v[k] - m);
    v[k] = p;
    lsum += p;
  }
#pragma unroll
  for (int off = 32; off > 0; off >>= 1) lsum += __shfl_xor(lsum, off);
  if (lane == 0) reds[wv] = lsum;
  __syncthreads();
  float inv = 1.f / (reds[0] + reds[1] + reds[2] + reds[3]);

  short8v o;
#pragma unroll
  for (int k = 0; k < 8; ++k) o[k] = f2bf(v[k] * inv);
  *(short8v*)(att + (long)row * NN + t * 8) = o;
}

// ---------------------------------------------------------------------------
extern "C" void kernel_launch(void* const* d_in, const int* in_sizes, int n_in,
                              void* d_out, int out_size, void* d_ws,
                              size_t ws_size, hipStream_t stream) {
  const int* node_feats = (const int*)d_in[0];
  const int* adjs = (const int*)d_in[1];
  const float* embed_table = (const float*)d_in[2];
  const float* W_heads = (const float*)d_in[3];
  const float* a_heads = (const float*)d_in[4];
  const float* W_out = (const float*)d_in[5];
  const float* a_out = (const float*)d_in[6];
  float* out = (float*)d_out;

  // workspace layout (~215 MB)
  char* p = (char*)d_ws;
  short* Wt_o = (short*)p;  p += (size_t)HID * (NHEADS * HID) * 2;       // 4.7 MB
  short* Wh_t = (short*)p;  p += (size_t)BB * HID * NN * 2;              // 25 MB
  short* att2 = (short*)p;  p += (size_t)BB * NN * NN * 2;               // 67 MB
  short* hcat = (short*)p;  p += (size_t)MTOT * NHEADS * HID * 2;        // 100 MB
  unsigned long long* padj = (unsigned long long*)p;
  p += (size_t)BB * NN * NN / 8;                                         // 4.2 MB
  float* P16 = (float*)p;   p += (size_t)NHEADS * 16384 * 16 * 4;        // 4 MB
  // zero region (ZERO_B*256 floats): Wh1, Wh2, TW1, TW2, pad
  float* Wh1 = (float*)p;   p += (size_t)16384 * 4;
  float* Wh2 = (float*)p;   p += (size_t)16384 * 4;
  float* TW1 = (float*)p;   p += (size_t)64 * 4;
  float* TW2 = (float*)p;   p += (size_t)64 * 4;
  p += (size_t)(ZERO_B * 256 - 2 * 16384 - 128) * 4;  // pad (zeroed)
  float* TWp = (float*)p;   p += (size_t)16 * VOCAB * NHEADS * HID * 4;  // 2.9 MB
  float* TW = (float*)p;    p += (size_t)VOCAB * NHEADS * HID * 4;
  unsigned long long* nfm = (unsigned long long*)p;
  p += (size_t)BB * VOCAB * 32 * 8;                                      // 30 KB
  if ((size_t)(p - (char*)d_ws) > ws_size) return;

  // 0) mega-setup: vectorized adj pack + zeros + vocab masks + transpose + TW
  setup_kernel<<<PACK_B + ZERO_B + NFM_B + TRAN_B + TW_B, 256, 0, stream>>>(
      adjs, padj, Wh1, node_feats, nfm, W_out, Wt_o, embed_table, W_heads,
      TWp);

  // 1) layer 1: TW reduce + a-dots (fused), popcount-P16, expand
  tw_finish_kernel<<<12, 256, 0, stream>>>(TWp, TW, a_heads, TW1, TW2);
  p16_kernel<<<16384 / 4, 256, 0, stream>>>(
      node_feats, (const unsigned*)padj, (const unsigned*)nfm, TW1, TW2, P16);
  hcat_expand<<<dim3(24, 128), 256, 0, stream>>>(TW, P16, hcat);

  // 2) output GAT layer (full-rank): proj2 -> Wh_t + Wh1/Wh2 atomics
  mfma_gemm<0><<<dim3(HID / 192, MTOT / 256, 1), 512, 0, stream>>>(
      hcat, Wt_o, NHEADS * HID, NHEADS * HID, NHEADS * HID, 0, 0,
      nullptr, Wh_t, a_out, Wh1, Wh2);
  attn_softmax_kernel<<<MTOT, 256, 0, stream>>>(Wh1, Wh2, padj, att2, out, 24);
  mfma_gemm<3><<<dim3(HID / 192, NN / 256, BB), 512, 0, stream>>>(
      att2, Wh_t, NN, NN, NN, (long)NN * NN, (long)HID * NN,
      out, nullptr, nullptr, nullptr, nullptr);
}

// Round 4
// 444.987 us; speedup vs baseline: 1.4891x; 1.0466x over previous
//
#include <hip/hip_runtime.h>
#include <math.h>

#define BB 8
#define NN 2048
#define HID 768
#define NHEADS 4
#define VOCAB 15
#define ALPHA 0.2f
#define NEGV -9e15f
#define MTOT (BB * NN)  // 16384

using short4v = __attribute__((ext_vector_type(4))) short;
using short8v = __attribute__((ext_vector_type(8))) short;
using f32x4 = __attribute__((ext_vector_type(4))) float;

__device__ __forceinline__ short f2bf(float f) {
  union { float f; unsigned u; } x;
  x.f = f;
  unsigned r = x.u + 0x7fffu + ((x.u >> 16) & 1u);
  return (short)(r >> 16);
}

__device__ __forceinline__ void cp16(const void* g, void* l) {
  __builtin_amdgcn_global_load_lds(
      (const __attribute__((address_space(1))) unsigned int*)g,
      (__attribute__((address_space(3))) unsigned int*)l, 16, 0, 0);
}

#define MEMFENCE asm volatile("" ::: "memory")
#define SBAR()                         \
  do {                                 \
    MEMFENCE;                          \
    __builtin_amdgcn_s_barrier();      \
    MEMFENCE;                          \
  } while (0)

// ---------------------------------------------------------------------------
// Mega-setup: [0,PACK_B) adjacency bit-pack (4096 vals/block, direct
// nibble->u16->u64, no compress); [+ZERO_B) zero accumulators; [+NFM_B)
// per-batch vocab bitmasks; [+TRAN_B) W_out transpose; [+TW_B) TW partials.
// ---------------------------------------------------------------------------
#define PACK_B 8192
#define ZERO_B 308
#define NFM_B 64
#define TRAN_B 2304  // 96 x 24 tiles of 32x32
#define TW_B 192     // 12 col-chunks x 16 k-chunks
__global__ __launch_bounds__(256) void setup_kernel(
    const int* __restrict__ adj, unsigned long long* __restrict__ packed,
    float* __restrict__ zbase, const int* __restrict__ nf,
    unsigned long long* __restrict__ nfm, const float* __restrict__ W_out,
    short* __restrict__ Wt_o, const float* __restrict__ table,
    const float* __restrict__ W_heads, float* __restrict__ TWp) {
  const int bid = blockIdx.x;
  const int tid = threadIdx.x;
  if (bid < PACK_B) {
    // 4096 adj values/block: thread t packs ints [base+16t, +16) into u16.
    __shared__ unsigned short us[256];
    long base = (long)bid * 4096;
    const int4* ap = (const int4*)(adj + base + tid * 16);
    unsigned nib16 = 0;
#pragma unroll
    for (int k = 0; k < 4; ++k) {
      int4 a = ap[k];
      unsigned nib = (a.x > 0 ? 1u : 0u) | (a.y > 0 ? 2u : 0u) |
                     (a.z > 0 ? 4u : 0u) | (a.w > 0 ? 8u : 0u);
      nib16 |= nib << (4 * k);
    }
    us[tid] = (unsigned short)nib16;
    __syncthreads();
    if (tid < 64) {
      unsigned long long w =
          (unsigned long long)us[4 * tid] |
          ((unsigned long long)us[4 * tid + 1] << 16) |
          ((unsigned long long)us[4 * tid + 2] << 32) |
          ((unsigned long long)us[4 * tid + 3] << 48);
      packed[(base >> 6) + tid] = w;
    }
  } else if (bid < PACK_B + ZERO_B) {
    zbase[(bid - PACK_B) * 256 + tid] = 0.f;
  } else if (bid < PACK_B + ZERO_B + NFM_B) {
    int r = bid - PACK_B - ZERO_B;  // 0..63
    int b = r >> 3, c = r & 7;
    int w = tid >> 6;
    int j = c * 256 + tid;
    int nfv = nf[b * NN + j];
#pragma unroll
    for (int v = 0; v < VOCAB; ++v) {
      unsigned long long m = __ballot(nfv == v);
      if ((tid & 63) == 0) nfm[((long)b * VOCAB + v) * 32 + c * 4 + w] = m;
    }
  } else if (bid < PACK_B + ZERO_B + NFM_B + TRAN_B) {
    // W_out transpose (3072x768 -> bf16 768x3072)
    __shared__ float t[32][33];
    int r2 = bid - PACK_B - ZERO_B - NFM_B;
    const int K = NHEADS * HID, N = HID;
    int k0 = (r2 % 96) * 32, n0 = (r2 / 96) * 32;
    int tx = tid & 31, ty = tid >> 5;
#pragma unroll
    for (int i = 0; i < 32; i += 8)
      t[ty + i][tx] = W_out[(long)(k0 + ty + i) * N + n0 + tx];
    __syncthreads();
#pragma unroll
    for (int i = 0; i < 32; i += 8)
      Wt_o[(long)(n0 + ty + i) * K + k0 + tx] = f2bf(t[tx][ty + i]);
  } else {
    // TW partial: col-chunk cx (256 cols), k-chunk ky (48 k) -> disjoint slot
    __shared__ float tbl[VOCAB][48];
    int r3 = bid - PACK_B - ZERO_B - NFM_B - TRAN_B;  // 0..191
    const int cx = r3 % 12, ky = r3 / 12;
    const int c = cx * 256 + tid;
    const int h = (cx * 256) / HID;
    const int n = c - h * HID;
    const int k0 = ky * 48;
    for (int idx = tid; idx < VOCAB * 48; idx += 256)
      tbl[idx / 48][idx % 48] = table[(idx / 48) * HID + k0 + idx % 48];
    __syncthreads();
    float acc[VOCAB];
#pragma unroll
    for (int v = 0; v < VOCAB; ++v) acc[v] = 0.f;
    const float* wp = W_heads + (long)h * HID * HID + (long)k0 * HID + n;
#pragma unroll 8
    for (int kk = 0; kk < 48; ++kk) {
      float w = wp[(long)kk * HID];
#pragma unroll
      for (int v = 0; v < VOCAB; ++v) acc[v] = fmaf(tbl[v][kk], w, acc[v]);
    }
#pragma unroll
    for (int v = 0; v < VOCAB; ++v)
      TWp[((long)ky * VOCAB + v) * (NHEADS * HID) + c] = acc[v];
  }
}

// ---------------------------------------------------------------------------
// Fused: reduce 16 TW partials -> TW, and accumulate a-dot partials into
// TW1/TW2 (zeroed by setup) via per-block reduce + atomicAdd. grid 12.
// ---------------------------------------------------------------------------
__global__ __launch_bounds__(256) void tw_finish_kernel(
    const float* __restrict__ TWp, float* __restrict__ TW,
    const float* __restrict__ a_heads, float* __restrict__ TW1,
    float* __restrict__ TW2) {
  const int tid = threadIdx.x;
  const int c = blockIdx.x * 256 + tid;  // 0..3071
  const int h = (blockIdx.x * 256) / HID;  // uniform per block
  const int n = c - h * HID;
  const float a1 = a_heads[h * 2 * HID + n];
  const float a2 = a_heads[h * 2 * HID + HID + n];
  const int lane = tid & 63;
  const int wv = tid >> 6;
  __shared__ float red[4][2 * VOCAB];

  float s1[VOCAB], s2[VOCAB];
#pragma unroll
  for (int v = 0; v < VOCAB; ++v) {
    float s = 0.f;
#pragma unroll
    for (int ky = 0; ky < 16; ++ky)
      s += TWp[((long)ky * VOCAB + v) * (NHEADS * HID) + c];
    TW[v * (NHEADS * HID) + c] = s;
    s1[v] = s * a1;
    s2[v] = s * a2;
  }
#pragma unroll
  for (int off = 1; off < 64; off <<= 1)
#pragma unroll
    for (int v = 0; v < VOCAB; ++v) {
      s1[v] += __shfl_xor(s1[v], off);
      s2[v] += __shfl_xor(s2[v], off);
    }
  if (lane == 0) {
#pragma unroll
    for (int v = 0; v < VOCAB; ++v) {
      red[wv][v] = s1[v];
      red[wv][VOCAB + v] = s2[v];
    }
  }
  __syncthreads();
  if (tid < 2 * VOCAB) {
    float s = red[0][tid] + red[1][tid] + red[2][tid] + red[3][tid];
    float* dst = (tid < VOCAB) ? (TW1 + h * VOCAB + tid)
                               : (TW2 + h * VOCAB + tid - VOCAB);
    atomicAdd(dst, s);
  }
}

// ---------------------------------------------------------------------------
// P16 via popcount: one wave per row; 15-value softmax for all 4 heads.
// ---------------------------------------------------------------------------
__global__ __launch_bounds__(256) void p16_kernel(
    const int* __restrict__ nf, const unsigned* __restrict__ padj32,
    const unsigned* __restrict__ nfm32, const float* __restrict__ TW1,
    const float* __restrict__ TW2, float* __restrict__ P16) {
  const int t = threadIdx.x;
  const int wv = t >> 6;
  const int lane = t & 63;
  const int rowm = blockIdx.x * 4 + wv;
  const int b = rowm >> 11;
  __shared__ float cnts[4][16];

  unsigned a = padj32[(long)rowm * 64 + lane];
  const unsigned* nb = nfm32 + (long)b * VOCAB * 64 + lane;
  int cnt[VOCAB];
#pragma unroll
  for (int v = 0; v < VOCAB; ++v) cnt[v] = __popc(a & nb[v * 64]);
#pragma unroll
  for (int off = 1; off < 64; off <<= 1)
#pragma unroll
    for (int v = 0; v < VOCAB; ++v) cnt[v] += __shfl_xor(cnt[v], off);
  int cntsum = 0;
#pragma unroll
  for (int v = 0; v < VOCAB; ++v) cntsum += cnt[v];
  const bool use_full = (cntsum == 0);  // wave-uniform
  if (use_full) {
#pragma unroll
    for (int v = 0; v < VOCAB; ++v) cnt[v] = __popc(nb[v * 64]);
#pragma unroll
    for (int off = 1; off < 64; off <<= 1)
#pragma unroll
      for (int v = 0; v < VOCAB; ++v) cnt[v] += __shfl_xor(cnt[v], off);
  }
  if (lane < 16) cnts[wv][lane] = (lane < VOCAB) ? (float)cnt[lane] : 0.f;
  __syncthreads();

  const int h = lane >> 4;
  const int v = lane & 15;
  const int nfi = nf[b * NN + (rowm & 2047)];
  float cvf = cnts[wv][v];
  bool valid = (v < VOCAB) && (cvf > 0.f);
  float logit = 0.f;
  if (!use_full) {
    float s = TW1[h * VOCAB + nfi] + ((v < VOCAB) ? TW2[h * VOCAB + v] : 0.f);
    logit = s > 0.f ? s : ALPHA * s;
  }
  float mv = valid ? logit : -INFINITY;
#pragma unroll
  for (int off = 1; off < 16; off <<= 1) mv = fmaxf(mv, __shfl_xor(mv, off));
  float pv = valid ? cvf * __expf(logit - mv) : 0.f;
  float sum = pv;
#pragma unroll
  for (int off = 1; off < 16; off <<= 1) sum += __shfl_xor(sum, off);
  if (v < VOCAB) P16[((long)h * 16384 + rowm) * 16 + v] = pv / sum;
}

// ---------------------------------------------------------------------------
// hcat[r][h*HID+colh] = ELU( sum_v P16[h][r][v] * TW[v][h*HID+colh] ) -> bf16
// TW slice held in registers (60 f32); P rows read as broadcast float4.
// ---------------------------------------------------------------------------
__global__ __launch_bounds__(256) void hcat_expand(
    const float* __restrict__ TW, const float* __restrict__ P16,
    short* __restrict__ hcat) {
  __shared__ float pl[128 * 16];
  const int c0 = blockIdx.x * 128;
  const int r0 = blockIdx.y * 128;
  const int h = c0 / HID;
  const int t = threadIdx.x;
  for (int idx = t; idx < 128 * 16; idx += 256)
    pl[idx] = P16[((long)h * 16384 + r0 + (idx >> 4)) * 16 + (idx & 15)];
  const int clb = (t & 31) * 4;
  const int rlb = (t >> 5) * 16;
  float twc[VOCAB][4];
#pragma unroll
  for (int vv = 0; vv < VOCAB; ++vv) {
    float4 q = *(const float4*)(TW + (long)vv * (NHEADS * HID) + c0 + clb);
    twc[vv][0] = q.x; twc[vv][1] = q.y; twc[vv][2] = q.z; twc[vv][3] = q.w;
  }
  __syncthreads();
#pragma unroll 4
  for (int rr = 0; rr < 16; ++rr) {
    int rl = rlb + rr;
    const float* pr = pl + rl * 16;
    float4 p0 = *(const float4*)(pr);
    float4 p1 = *(const float4*)(pr + 4);
    float4 p2 = *(const float4*)(pr + 8);
    float4 p3 = *(const float4*)(pr + 12);
    float pv[VOCAB] = {p0.x, p0.y, p0.z, p0.w, p1.x, p1.y, p1.z, p1.w,
                       p2.x, p2.y, p2.z, p2.w, p3.x, p3.y, p3.z};
    short4v o;
#pragma unroll
    for (int cc = 0; cc < 4; ++cc) {
      float s = 0.f;
#pragma unroll
      for (int vv = 0; vv < VOCAB; ++vv) s = fmaf(pv[vv], twc[vv][cc], s);
      s = s > 0.f ? s : (__expf(s) - 1.f);
      o[cc] = f2bf(s);
    }
    *(short4v*)(hcat + (long)(r0 + rl) * (NHEADS * HID) + c0 + clb) = o;
  }
}

// ---------------------------------------------------------------------------
// bf16 MFMA GEMM, 256x256 tile, BK=64, 512 threads (8 waves, 2Mx4N).
// 3 phases/K-tile: {f0: stage B(t+1) || read a-lo+b0 || MFMA Q00(16)},
// {f1: read b1+a-hi || MFMA Q01+Q11(32)}, {f2: stage A(t+2) || MFMA Q10(16)}.
// Counted vmcnt(4) once per K-tile; K-chunk XOR swizzle via pre-swizzled
// global source + swizzled ds_read. Double-buffered 128 KiB LDS.
//   Ledger (tile t in buf[t&1]): B(t+1)@f0, A(t+2)@f2; f2's vmcnt(4)
//   drains A(t+1)+B(t+1), keeps A(t+2) in flight. A(t)'s last read (a-hi)
//   completes before f1's closing barrier, so stageA(t+2) at f2 is safe.
// MODE 0: a-dot atomics + transposed bf16 Ct [bb][colh][row] (layer 2).
// MODE 3: fused ELU + mean-pool: atomicAdd Cf[z*HID + col].
// ---------------------------------------------------------------------------
template <int MODE>
__global__ __launch_bounds__(512, 2) void mfma_gemm(
    const short* __restrict__ A, const short* __restrict__ B,
    int K, int lda, int ldb, long sA, long sB,
    float* __restrict__ Cf, short* __restrict__ Ct,
    const float* __restrict__ a_vec, float* __restrict__ Wh1g,
    float* __restrict__ Wh2g) {
  __shared__ short lds[2][2][16384];  // [buf][A/B][256 rows * 64 k] = 128 KiB

  const int gx = gridDim.x, gy = gridDim.y;
  int linb = blockIdx.x + gx * (blockIdx.y + gy * blockIdx.z);
  const int per = (gx * gy * gridDim.z) >> 3;
  int work = (linb & 7) * per + (linb >> 3);
  int bx, by, z;
  if constexpr (MODE == 0) {
    bx = work / gy;  // bx-major: each XCD works within ~1 B panel
    by = work % gy;
    z = 0;
  } else {
    bx = work % gx;
    int tm = work / gx;
    by = tm % gy;
    z = tm / gy;  // one batch per XCD: B panel L2-resident
  }

  A += (long)z * sA;
  B += (long)z * sB;

  const int tid = threadIdx.x;
  const int m0 = by * 256;
  const int n0 = bx * 256;
  const int lane = tid & 63;
  const int wid = tid >> 6;
  const int wr = wid >> 2;  // 0..1  (M half)
  const int wc = wid & 3;   // 0..3  (N quarter)
  const int l15 = lane & 15;
  const int quad = lane >> 4;
  const int NT = K >> 6;
  const int cbase = (quad ^ (l15 & 7)) << 3;

  auto stageA = [&](int kt, int h) {
    const short* src = A + (long)(m0 + h * 128) * lda + kt * 64;
    short* dst = &lds[kt & 1][0][h * 8192];
#pragma unroll
    for (int it = 0; it < 2; ++it) {
      int r = it * 64 + (tid >> 3);
      int s = tid & 7;
      cp16(src + (long)r * lda + ((s ^ (r & 7)) << 3),
           dst + (it * 512 + tid) * 8);
    }
  };
  auto stageB = [&](int kt, int h) {
    const short* src = B + (long)(n0 + h * 128) * ldb + kt * 64;
    short* dst = &lds[kt & 1][1][h * 8192];
#pragma unroll
    for (int it = 0; it < 2; ++it) {
      int r = it * 64 + (tid >> 3);
      int s = tid & 7;
      cp16(src + (long)r * ldb + ((s ^ (r & 7)) << 3),
           dst + (it * 512 + tid) * 8);
    }
  };

  f32x4 acc[8][4];
#pragma unroll
  for (int i = 0; i < 8; ++i)
#pragma unroll
    for (int j = 0; j < 4; ++j) acc[i][j] = (f32x4){0.f, 0.f, 0.f, 0.f};

  // prologue: tile0 fully, tile1's A (kept in flight across the wait)
  stageA(0, 0); stageA(0, 1);
  stageB(0, 0); stageB(0, 1);
  stageA(1, 0); stageA(1, 1);
  asm volatile("s_waitcnt vmcnt(4)" ::: "memory");
  SBAR();

#pragma unroll 1
  for (int t = 0; t < NT; ++t) {
    const int p = t & 1;
    const short* Ab = &lds[p][0][0];
    const short* Bb = &lds[p][1][0];
    short8v alo[4][2], ahi[4][2], b0[2][2], b1[2][2];

    // ---- f0: issue B(t+1); read a-lo + b0; MFMA Q00 (16) ----
    if (t + 1 < NT) { stageB(t + 1, 0); stageB(t + 1, 1); }
#pragma unroll
    for (int ii = 0; ii < 4; ++ii) {
      int ro = (wr * 128 + ii * 16 + l15) * 64;
      alo[ii][0] = *(const short8v*)(Ab + ro + cbase);
      alo[ii][1] = *(const short8v*)(Ab + ro + (cbase ^ 32));
    }
#pragma unroll
    for (int jj = 0; jj < 2; ++jj) {
      int ro = (wc * 64 + jj * 16 + l15) * 64;
      b0[jj][0] = *(const short8v*)(Bb + ro + cbase);
      b0[jj][1] = *(const short8v*)(Bb + ro + (cbase ^ 32));
    }
    SBAR();
    asm volatile("s_waitcnt lgkmcnt(0)" ::: "memory");
    __builtin_amdgcn_sched_barrier(0);
    __builtin_amdgcn_s_setprio(1);
#pragma unroll
    for (int ii = 0; ii < 4; ++ii)
#pragma unroll
      for (int jj = 0; jj < 2; ++jj) {
        acc[ii][jj] = __builtin_amdgcn_mfma_f32_16x16x32_bf16(
            alo[ii][0], b0[jj][0], acc[ii][jj], 0, 0, 0);
        acc[ii][jj] = __builtin_amdgcn_mfma_f32_16x16x32_bf16(
            alo[ii][1], b0[jj][1], acc[ii][jj], 0, 0, 0);
      }
    __builtin_amdgcn_sched_barrier(0);
    __builtin_amdgcn_s_setprio(0);
    SBAR();

    // ---- f1: read b1 + a-hi; MFMA Q01 (16) + Q11 (16) ----
#pragma unroll
    for (int jj = 0; jj < 2; ++jj) {
      int ro = (wc * 64 + 32 + jj * 16 + l15) * 64;
      b1[jj][0] = *(const short8v*)(Bb + ro + cbase);
      b1[jj][1] = *(const short8v*)(Bb + ro + (cbase ^ 32));
    }
#pragma unroll
    for (int ii = 0; ii < 4; ++ii) {
      int ro = (wr * 128 + 64 + ii * 16 + l15) * 64;
      ahi[ii][0] = *(const short8v*)(Ab + ro + cbase);
      ahi[ii][1] = *(const short8v*)(Ab + ro + (cbase ^ 32));
    }
    SBAR();
    asm volatile("s_waitcnt lgkmcnt(0)" ::: "memory");
    __builtin_amdgcn_sched_barrier(0);
    __builtin_amdgcn_s_setprio(1);
#pragma unroll
    for (int ii = 0; ii < 4; ++ii)
#pragma unroll
      for (int jj = 0; jj < 2; ++jj) {
        acc[ii][2 + jj] = __builtin_amdgcn_mfma_f32_16x16x32_bf16(
            alo[ii][0], b1[jj][0], acc[ii][2 + jj], 0, 0, 0);
        acc[ii][2 + jj] = __builtin_amdgcn_mfma_f32_16x16x32_bf16(
            alo[ii][1], b1[jj][1], acc[ii][2 + jj], 0, 0, 0);
      }
#pragma unroll
    for (int ii = 0; ii < 4; ++ii)
#pragma unroll
      for (int jj = 0; jj < 2; ++jj) {
        acc[4 + ii][2 + jj] = __builtin_amdgcn_mfma_f32_16x16x32_bf16(
            ahi[ii][0], b1[jj][0], acc[4 + ii][2 + jj], 0, 0, 0);
        acc[4 + ii][2 + jj] = __builtin_amdgcn_mfma_f32_16x16x32_bf16(
            ahi[ii][1], b1[jj][1], acc[4 + ii][2 + jj], 0, 0, 0);
      }
    __builtin_amdgcn_sched_barrier(0);
    __builtin_amdgcn_s_setprio(0);
    SBAR();

    // ---- f2: issue A(t+2) (buf p dead); MFMA Q10 (16); counted drain ----
    if (t + 2 < NT) { stageA(t + 2, 0); stageA(t + 2, 1); }
    __builtin_amdgcn_s_setprio(1);
#pragma unroll
    for (int ii = 0; ii < 4; ++ii)
#pragma unroll
      for (int jj = 0; jj < 2; ++jj) {
        acc[4 + ii][jj] = __builtin_amdgcn_mfma_f32_16x16x32_bf16(
            ahi[ii][0], b0[jj][0], acc[4 + ii][jj], 0, 0, 0);
        acc[4 + ii][jj] = __builtin_amdgcn_mfma_f32_16x16x32_bf16(
            ahi[ii][1], b0[jj][1], acc[4 + ii][jj], 0, 0, 0);
      }
    __builtin_amdgcn_sched_barrier(0);
    __builtin_amdgcn_s_setprio(0);
    if (t + 2 < NT) {
      asm volatile("s_waitcnt vmcnt(4)" ::: "memory");
    } else if (t + 1 < NT) {
      asm volatile("s_waitcnt vmcnt(0)" ::: "memory");
    }
    SBAR();
  }

  // ---- epilogues (C/D layout: col=l15, row=quad*4+reg per 16x16 frag;
  //      acc[mi][nj] covers rows wr*128+mi*16, cols wc*64+nj*16) ----
  if constexpr (MODE == 3) {
#pragma unroll
    for (int nj = 0; nj < 4; ++nj) {
      int col = n0 + wc * 64 + nj * 16 + l15;
      float s = 0.f;
#pragma unroll
      for (int mi = 0; mi < 8; ++mi)
#pragma unroll
        for (int reg = 0; reg < 4; ++reg) {
          float v = acc[mi][nj][reg];
          s += v > 0.f ? v : (__expf(v) - 1.f);
        }
      s += __shfl_xor(s, 16);
      s += __shfl_xor(s, 32);
      if (quad == 0) atomicAdd(Cf + (long)z * HID + col, s * (1.0f / NN));
    }
  } else {  // MODE 0: a-dot atomics + direct transposed Ct store
    float a1v[4], a2v[4];
#pragma unroll
    for (int nj = 0; nj < 4; ++nj) {
      int colh = n0 + wc * 64 + nj * 16 + l15;  // < 768
      a1v[nj] = a_vec[colh];
      a2v[nj] = a_vec[HID + colh];
    }
#pragma unroll
    for (int mi = 0; mi < 8; ++mi) {
      int rb = m0 + wr * 128 + mi * 16 + quad * 4;
#pragma unroll
      for (int reg = 0; reg < 4; ++reg) {
        float s1 = 0.f, s2 = 0.f;
#pragma unroll
        for (int nj = 0; nj < 4; ++nj) {
          s1 = fmaf(acc[mi][nj][reg], a1v[nj], s1);
          s2 = fmaf(acc[mi][nj][reg], a2v[nj], s2);
        }
#pragma unroll
        for (int off = 1; off < 16; off <<= 1) {
          s1 += __shfl_xor(s1, off);
          s2 += __shfl_xor(s2, off);
        }
        if (l15 == 0) {
          atomicAdd(Wh1g + rb + reg, s1);
          atomicAdd(Wh2g + rb + reg, s2);
        }
      }
    }
    const int bb = m0 >> 11;
    const int ml0 = (m0 & 2047) + wr * 128;
#pragma unroll
    for (int mi = 0; mi < 8; ++mi) {
#pragma unroll
      for (int nj = 0; nj < 4; ++nj) {
        int colh = n0 + wc * 64 + nj * 16 + l15;
        short4v pk;
#pragma unroll
        for (int reg = 0; reg < 4; ++reg) pk[reg] = f2bf(acc[mi][nj][reg]);
        *(short4v*)(Ct + ((long)bb * HID + colh) * NN + ml0 + mi * 16 +
                    quad * 4) = pk;
      }
    }
  }
}

// ---------------------------------------------------------------------------
// Layer-2 row softmax (materializing, bf16 att). 8 rows/block (same batch),
// Wh2 row cached in registers. grid 2048. Blocks [0,zn) also zero zA.
// ---------------------------------------------------------------------------
__global__ __launch_bounds__(256) void attn_softmax_kernel(
    const float* __restrict__ Wh1, const float* __restrict__ Wh2,
    const unsigned long long* __restrict__ packed, short* __restrict__ att,
    float* __restrict__ zA, int zn) {
  const int bid = blockIdx.x;
  const int t = threadIdx.x;
  if (bid < zn) zA[bid * 256 + t] = 0.f;
  const int b = bid >> 8;
  const int row0 = bid * 8;
  const int lane = t & 63;
  const int wv = t >> 6;
  const float* wh2b = Wh2 + b * NN;

  float4 wa = ((const float4*)(wh2b + t * 8))[0];
  float4 wb = ((const float4*)(wh2b + t * 8))[1];
  float w[8] = {wa.x, wa.y, wa.z, wa.w, wb.x, wb.y, wb.z, wb.w};

  __shared__ float redm[4], reds[4];
#pragma unroll 1
  for (int r = 0; r < 8; ++r) {
    const int row = row0 + r;
    unsigned m8 = ((const unsigned char*)(packed + (long)row * 32))[t];
    float wh1 = Wh1[row];
    float v[8];
    float lmax = -INFINITY;
#pragma unroll
    for (int k = 0; k < 8; ++k) {
      float s = wh1 + w[k];
      s = s > 0.f ? s : ALPHA * s;
      s = ((m8 >> k) & 1u) ? s : NEGV;
      v[k] = s;
      lmax = fmaxf(lmax, s);
    }
#pragma unroll
    for (int off = 32; off > 0; off >>= 1)
      lmax = fmaxf(lmax, __shfl_xor(lmax, off));
    if (lane == 0) redm[wv] = lmax;
    __syncthreads();
    float m = fmaxf(fmaxf(redm[0], redm[1]), fmaxf(redm[2], redm[3]));

    float lsum = 0.f;
#pragma unroll
    for (int k = 0; k < 8; ++k) {
      float p = __expf(v[k] - m);
      v[k] = p;
      lsum += p;
    }
#pragma unroll
    for (int off = 32; off > 0; off >>= 1) lsum += __shfl_xor(lsum, off);
    if (lane == 0) reds[wv] = lsum;
    __syncthreads();
    float inv = 1.f / (reds[0] + reds[1] + reds[2] + reds[3]);

    short8v o;
#pragma unroll
    for (int k = 0; k < 8; ++k) o[k] = f2bf(v[k] * inv);
    *(short8v*)(att + (long)row * NN + t * 8) = o;
  }
}

// ---------------------------------------------------------------------------
extern "C" void kernel_launch(void* const* d_in, const int* in_sizes, int n_in,
                              void* d_out, int out_size, void* d_ws,
                              size_t ws_size, hipStream_t stream) {
  const int* node_feats = (const int*)d_in[0];
  const int* adjs = (const int*)d_in[1];
  const float* embed_table = (const float*)d_in[2];
  const float* W_heads = (const float*)d_in[3];
  const float* a_heads = (const float*)d_in[4];
  const float* W_out = (const float*)d_in[5];
  const float* a_out = (const float*)d_in[6];
  float* out = (float*)d_out;

  // workspace layout (~215 MB)
  char* p = (char*)d_ws;
  short* Wt_o = (short*)p;  p += (size_t)HID * (NHEADS * HID) * 2;       // 4.7 MB
  short* Wh_t = (short*)p;  p += (size_t)BB * HID * NN * 2;              // 25 MB
  short* att2 = (short*)p;  p += (size_t)BB * NN * NN * 2;               // 67 MB
  short* hcat = (short*)p;  p += (size_t)MTOT * NHEADS * HID * 2;        // 100 MB
  unsigned long long* padj = (unsigned long long*)p;
  p += (size_t)BB * NN * NN / 8;                                         // 4.2 MB
  float* P16 = (float*)p;   p += (size_t)NHEADS * 16384 * 16 * 4;        // 4 MB
  // zero region (ZERO_B*256 floats): Wh1, Wh2, TW1, TW2, pad
  float* Wh1 = (float*)p;   p += (size_t)16384 * 4;
  float* Wh2 = (float*)p;   p += (size_t)16384 * 4;
  float* TW1 = (float*)p;   p += (size_t)64 * 4;
  float* TW2 = (float*)p;   p += (size_t)64 * 4;
  p += (size_t)(ZERO_B * 256 - 2 * 16384 - 128) * 4;  // pad (zeroed)
  float* TWp = (float*)p;   p += (size_t)16 * VOCAB * NHEADS * HID * 4;  // 2.9 MB
  float* TW = (float*)p;    p += (size_t)VOCAB * NHEADS * HID * 4;
  unsigned long long* nfm = (unsigned long long*)p;
  p += (size_t)BB * VOCAB * 32 * 8;                                      // 30 KB
  if ((size_t)(p - (char*)d_ws) > ws_size) return;

  // 0) mega-setup: vectorized adj pack + zeros + vocab masks + transpose + TW
  setup_kernel<<<PACK_B + ZERO_B + NFM_B + TRAN_B + TW_B, 256, 0, stream>>>(
      adjs, padj, Wh1, node_feats, nfm, W_out, Wt_o, embed_table, W_heads,
      TWp);

  // 1) layer 1: TW reduce + a-dots (fused), popcount-P16, expand
  tw_finish_kernel<<<12, 256, 0, stream>>>(TWp, TW, a_heads, TW1, TW2);
  p16_kernel<<<16384 / 4, 256, 0, stream>>>(
      node_feats, (const unsigned*)padj, (const unsigned*)nfm, TW1, TW2, P16);
  hcat_expand<<<dim3(24, 128), 256, 0, stream>>>(TW, P16, hcat);

  // 2) output GAT layer (full-rank): proj2 -> Wh_t + Wh1/Wh2 atomics
  mfma_gemm<0><<<dim3(HID / 256, MTOT / 256, 1), 512, 0, stream>>>(
      hcat, Wt_o, NHEADS * HID, NHEADS * HID, NHEADS * HID, 0, 0,
      nullptr, Wh_t, a_out, Wh1, Wh2);
  attn_softmax_kernel<<<MTOT / 8, 256, 0, stream>>>(Wh1, Wh2, padj, att2, out,
                                                    24);
  mfma_gemm<3><<<dim3(HID / 256, NN / 256, BB), 512, 0, stream>>>(
      att2, Wh_t, NN, NN, NN, (long)NN * NN, (long)HID * NN,
      out, nullptr, nullptr, nullptr, nullptr);
}